// Round 10
// baseline (558.442 us; speedup 1.0000x reference)
//
#include <hip/hip_runtime.h>
#include <hip/hip_bf16.h>

#define N_NODES 200000
#define N_EDGES 600000
#define EMB 128
#define HID 128
#define N_RELS 64
#define N_MOTIFS 512
#define N_CENTERS 256
#define NCLS 16

#define SCAN_C 512
#define NB_SCAN ((N_NODES + SCAN_C - 1) / SCAN_C)   // 391

typedef unsigned short u16;
typedef __attribute__((ext_vector_type(8))) short short8;   // 8 x bf16
typedef __attribute__((ext_vector_type(4))) float f32x4;

__device__ __forceinline__ float bf2f(u16 u) {
    unsigned int i = ((unsigned int)u) << 16;
    float f; __builtin_memcpy(&f, &i, 4); return f;
}
__device__ __forceinline__ u16 f2bf(float f) {
    unsigned int x; __builtin_memcpy(&x, &f, 4);
    x += 0x7fffu + ((x >> 16) & 1u);          // RNE
    return (u16)(x >> 16);
}

// bf16 weight-table offsets (elements) inside ws
#define O_LINW   0
#define O_LINB   16384
#define O_C1W    16512
#define O_C1B    32896
#define O_C2W    33024
#define O_C2B    49408
#define O_EW     49536
#define O_EB     65920
#define O_MW     65984
#define O_MB     131520
#define O_NW     132032
#define O_NB     134080
#define N_WB     134096

// ---------------------------------------------------------------------------
// merged prologue: blocks 0..63 compute rel_lin f32 AND bf16 copy; the rest
// convert the 12 weight arrays to the bf16 table. 128 threads/block.
// ---------------------------------------------------------------------------
__global__ void k_pre(const float* __restrict__ rel_emb,
                      const float* __restrict__ lw, const float* __restrict__ lb,
                      const float* __restrict__ c1w, const float* __restrict__ c1b,
                      const float* __restrict__ c2w, const float* __restrict__ c2b,
                      const float* __restrict__ ew, const float* __restrict__ eb,
                      const float* __restrict__ mw, const float* __restrict__ mb,
                      const float* __restrict__ nw, const float* __restrict__ nb,
                      float* __restrict__ rel_lin, u16* __restrict__ rel_bf,
                      u16* __restrict__ wb)
{
    if (blockIdx.x < 64) {
        __shared__ float e[EMB];
        const int r = blockIdx.x, h = threadIdx.x;
        e[h] = rel_emb[r * EMB + h];
        __syncthreads();
        const float* wr = lw + (size_t)h * EMB;
        float acc = lb[h];
        #pragma unroll
        for (int k0 = 0; k0 < EMB; k0 += 4) {
            f32x4 wv = *(const f32x4*)(wr + k0);
            #pragma unroll
            for (int j = 0; j < 4; ++j) acc += e[k0 + j] * wv[j];
        }
        rel_lin[r * HID + h] = acc;
        rel_bf[r * HID + h] = f2bf(acc);
        return;
    }
    const int t = (blockIdx.x - 64) * 128 + threadIdx.x;
    if (t >= N_WB) return;
    float v;
    if      (t < O_LINB) v = lw[t - O_LINW];
    else if (t < O_C1W)  v = lb[t - O_LINB];
    else if (t < O_C1B)  v = c1w[t - O_C1W];
    else if (t < O_C2W)  v = c1b[t - O_C1B];
    else if (t < O_C2B)  v = c2w[t - O_C2W];
    else if (t < O_EW)   v = c2b[t - O_C2B];
    else if (t < O_EB)   v = ew[t - O_EW];
    else if (t < O_MW)   v = eb[t - O_EB];
    else if (t < O_MB)   v = mw[t - O_MW];
    else if (t < O_NW)   v = mb[t - O_MB];
    else if (t < O_NB)   v = nw[t - O_NW];
    else                 v = nb[t - O_NB];
    wb[t] = f2bf(v);
}

// ---------------------------------------------------------------------------
// CSR build
// ---------------------------------------------------------------------------
__global__ void k_hist(const int* __restrict__ dst, int* __restrict__ deg)
{
    const int e = blockIdx.x * 256 + threadIdx.x;
    if (e < N_EDGES) atomicAdd(&deg[dst[e]], 1);
}

__global__ void k_scan1(const int* __restrict__ deg, int* __restrict__ bsum)
{
    __shared__ int sd[256];
    const int t = threadIdx.x, base = blockIdx.x * SCAN_C;
    int v = 0;
    int i0 = base + t, i1 = base + 256 + t;
    if (i0 < N_NODES) v += deg[i0];
    if (i1 < N_NODES) v += deg[i1];
    sd[t] = v; __syncthreads();
    for (int s = 128; s > 0; s >>= 1) {
        if (t < s) sd[t] += sd[t + s];
        __syncthreads();
    }
    if (t == 0) bsum[blockIdx.x] = sd[0];
}

__global__ void k_scan2(int* __restrict__ bsum, int* __restrict__ row_ptr)
{
    __shared__ int sh[512];
    const int t = threadIdx.x;
    int v = (t < NB_SCAN) ? bsum[t] : 0;
    sh[t] = v;
    for (int off = 1; off < 512; off <<= 1) {
        __syncthreads();
        int a = (t >= off) ? sh[t - off] : 0;
        __syncthreads();
        sh[t] += a;
    }
    __syncthreads();
    if (t < NB_SCAN) bsum[t] = sh[t] - v;         // exclusive
    if (t == 511) row_ptr[N_NODES] = sh[511];     // total = E
}

__global__ void k_scan3(const int* __restrict__ deg, const int* __restrict__ bsum,
                        int* __restrict__ row_ptr)
{
    __shared__ int sh[256];
    const int t = threadIdx.x, base = blockIdx.x * SCAN_C;
    const int i0 = base + 2 * t, i1 = i0 + 1;
    int d0 = (i0 < N_NODES) ? deg[i0] : 0;
    int d1 = (i1 < N_NODES) ? deg[i1] : 0;
    int p = d0 + d1;
    sh[t] = p;
    for (int off = 1; off < 256; off <<= 1) {
        __syncthreads();
        int a = (t >= off) ? sh[t - off] : 0;
        __syncthreads();
        sh[t] += a;
    }
    __syncthreads();
    const int off = bsum[blockIdx.x] + sh[t] - p;  // exclusive within block
    if (i0 < N_NODES) row_ptr[i0] = off;
    if (i1 < N_NODES) row_ptr[i1] = off + d0;
}

__global__ void k_fill(const int* __restrict__ src, const int* __restrict__ dst,
                       const int* __restrict__ rid, const int* __restrict__ row_ptr,
                       int* __restrict__ cur, int* __restrict__ srcrid)
{
    const int e = blockIdx.x * 256 + threadIdx.x;
    if (e >= N_EDGES) return;
    const int d = dst[e];
    const int pos = row_ptr[d] + atomicAdd(&cur[d], 1);
    srcrid[pos] = src[e] * 64 + rid[e];
}

// ---------------------------------------------------------------------------
// x0 = bf16( node_emb[ids] @ lin_w^T + lin_b )
// ---------------------------------------------------------------------------
__global__ __launch_bounds__(256) void k_lin(
    const float* __restrict__ emb, const int* __restrict__ ids,
    const u16* __restrict__ w, const u16* __restrict__ bias,
    u16* __restrict__ out)
{
    const int wid = threadIdx.x >> 6, lane = threadIdx.x & 63;
    const int r15 = lane & 15, kg = (lane >> 4) * 8;
    const int arow = blockIdx.x * 64 + wid * 16 + r15;
    const int srow = ids[arow];
    const float* ar = emb + (size_t)srow * EMB + kg;
    short8 a[4];
    #pragma unroll
    for (int kk = 0; kk < 4; ++kk) {
        f32x4 a0 = *(const f32x4*)(ar + kk * 32);
        f32x4 a1 = *(const f32x4*)(ar + kk * 32 + 4);
        short8 t;
        #pragma unroll
        for (int j = 0; j < 4; ++j) { t[j] = (short)f2bf(a0[j]); t[4 + j] = (short)f2bf(a1[j]); }
        a[kk] = t;
    }
    f32x4 acc[8];
    #pragma unroll
    for (int nb = 0; nb < 8; ++nb) acc[nb] = (f32x4){0.f, 0.f, 0.f, 0.f};
    #pragma unroll
    for (int nb = 0; nb < 8; ++nb) {
        const u16* wr = w + (size_t)(nb * 16 + r15) * EMB + kg;
        #pragma unroll
        for (int kk = 0; kk < 4; ++kk) {
            short8 bv = *(const short8*)(wr + kk * 32);
            acc[nb] = __builtin_amdgcn_mfma_f32_16x16x32_bf16(a[kk], bv, acc[nb], 0, 0, 0);
        }
    }
    const int ob = blockIdx.x * 64 + wid * 16 + (lane >> 4) * 4;
    #pragma unroll
    for (int nb = 0; nb < 8; ++nb) {
        const int col = nb * 16 + r15;
        const float bn = bf2f(bias[col]);
        #pragma unroll
        for (int r = 0; r < 4; ++r)
            out[(size_t)(ob + r) * HID + col] = f2bf(acc[nb][r] + bn);
    }
}

// ---------------------------------------------------------------------------
// EDGE-PARALLEL message build (round 10): thread = (CSR position p, quarter q)
//   msg[p][c] = bf16( relu( x[src_p][c] + rel_bf[rid_p][c] ) )
// No loops, no dependent chains beyond one gather; coalesced writes.
// ---------------------------------------------------------------------------
__global__ __launch_bounds__(256) void k_msg2(
    const u16* __restrict__ x, const u16* __restrict__ relb,
    const int* __restrict__ srcrid, u16* __restrict__ msg)
{
    const int t = blockIdx.x * 256 + threadIdx.x;
    const int p = t >> 2;
    const int q = (t & 3) * 32;
    const int v = srcrid[p];
    const int s = v >> 6, r = v & 63;
    const u16* xp = x + (size_t)s * HID + q;
    const u16* rp = relb + r * HID + q;
    u16* mp = msg + (size_t)p * HID + q;
    #pragma unroll
    for (int c = 0; c < 4; ++c) {
        short8 xv = *(const short8*)(xp + c * 8);
        short8 rv = *(const short8*)(rp + c * 8);
        short8 o;
        #pragma unroll
        for (int j = 0; j < 8; ++j)
            o[j] = (short)f2bf(fmaxf(bf2f((u16)xv[j]) + bf2f((u16)rv[j]), 0.f));
        *(short8*)(mp + c * 8) = o;
    }
}

// ---------------------------------------------------------------------------
// FUSED segment-sum + conv (round 10): stream msg rows (sequential p, no
// pointer-chase), accumulate in A-frag layout, MFMA conv, natural-order IO.
// No rel table, no srcrid, zero LDS.
// ---------------------------------------------------------------------------
__global__ __launch_bounds__(256) void k_fuse2(
    const u16* __restrict__ x, const u16* __restrict__ msg,
    const int* __restrict__ row_ptr,
    const u16* __restrict__ w, const u16* __restrict__ bias,
    u16* __restrict__ out, const int do_relu)
{
    const int wid = threadIdx.x >> 6, lane = threadIdx.x & 63;
    const int r15 = lane & 15;
    const int kg = (lane >> 4) * 8;
    const int n = blockIdx.x * 64 + wid * 16 + r15;
    const int pbeg = row_ptr[n], pend = row_ptr[n + 1];

    float acc[32];
    #pragma unroll
    for (int j = 0; j < 32; ++j) acc[j] = 0.f;

    int p = pbeg;
    for (; p + 2 <= pend; p += 2) {
        const u16* m0 = msg + (size_t)p * HID + kg;
        const u16* m1 = m0 + HID;
        short8 v0[4], v1[4];
        #pragma unroll
        for (int kk = 0; kk < 4; ++kk) { v0[kk] = *(const short8*)(m0 + kk * 32);
                                         v1[kk] = *(const short8*)(m1 + kk * 32); }
        #pragma unroll
        for (int kk = 0; kk < 4; ++kk)
            #pragma unroll
            for (int j = 0; j < 8; ++j)
                acc[kk * 8 + j] += bf2f((u16)v0[kk][j]) + bf2f((u16)v1[kk][j]);
    }
    if (p < pend) {
        const u16* m0 = msg + (size_t)p * HID + kg;
        #pragma unroll
        for (int kk = 0; kk < 4; ++kk) {
            short8 v0 = *(const short8*)(m0 + kk * 32);
            #pragma unroll
            for (int j = 0; j < 8; ++j) acc[kk * 8 + j] += bf2f((u16)v0[j]);
        }
    }

    // own x row + convert -> A-frags
    short8 a[4];
    {
        const u16* xp = x + (size_t)n * HID + kg;
        #pragma unroll
        for (int kk = 0; kk < 4; ++kk) {
            short8 xv = *(const short8*)(xp + kk * 32);
            short8 t;
            #pragma unroll
            for (int j = 0; j < 8; ++j) t[j] = (short)f2bf(acc[kk * 8 + j] + bf2f((u16)xv[j]));
            a[kk] = t;
        }
    }

    // MFMA conv
    f32x4 accm[8];
    #pragma unroll
    for (int nb = 0; nb < 8; ++nb) accm[nb] = (f32x4){0.f, 0.f, 0.f, 0.f};
    #pragma unroll
    for (int nb = 0; nb < 8; ++nb) {
        const u16* wr = w + (size_t)(nb * 16 + r15) * HID + kg;
        #pragma unroll
        for (int kk = 0; kk < 4; ++kk) {
            short8 bv = *(const short8*)(wr + kk * 32);
            accm[nb] = __builtin_amdgcn_mfma_f32_16x16x32_bf16(a[kk], bv, accm[nb], 0, 0, 0);
        }
    }
    const int ob = blockIdx.x * 64 + wid * 16 + (lane >> 4) * 4;
    #pragma unroll
    for (int nb = 0; nb < 8; ++nb) {
        const int col = nb * 16 + r15;
        const float bn = bf2f(bias[col]);
        #pragma unroll
        for (int r = 0; r < 4; ++r) {
            float v = accm[nb][r] + bn;
            if (do_relu) v = fmaxf(v, 0.f);
            out[(size_t)(ob + r) * HID + col] = f2bf(v);
        }
    }
}

// ---------------------------------------------------------------------------
// heads precompute:  y (bf16) [n][0:64]=x2.ew_src, [64:128]=x2.ew_dst;
//                    node_out[n] = x2[n].nw + nb  (f32)
// ---------------------------------------------------------------------------
__global__ __launch_bounds__(256) void k_heads(
    const u16* __restrict__ x2, const u16* __restrict__ ew,
    const u16* __restrict__ nw, const u16* __restrict__ nbias,
    u16* __restrict__ y, float* __restrict__ node_out)
{
    const int wid = threadIdx.x >> 6, lane = threadIdx.x & 63;
    const int r15 = lane & 15, kg = (lane >> 4) * 8;
    const int arow = blockIdx.x * 64 + wid * 16 + r15;
    const u16* xr = x2 + (size_t)arow * HID + kg;
    short8 a[4];
    #pragma unroll
    for (int kk = 0; kk < 4; ++kk) a[kk] = *(const short8*)(xr + kk * 32);

    f32x4 accs[4], accd[4], accn;
    #pragma unroll
    for (int nb = 0; nb < 4; ++nb) {
        accs[nb] = (f32x4){0.f, 0.f, 0.f, 0.f};
        accd[nb] = (f32x4){0.f, 0.f, 0.f, 0.f};
    }
    accn = (f32x4){0.f, 0.f, 0.f, 0.f};

    #pragma unroll
    for (int nb = 0; nb < 4; ++nb) {
        const u16* wr = ew + (size_t)(nb * 16 + r15) * 256 + kg;
        #pragma unroll
        for (int kk = 0; kk < 4; ++kk) {
            short8 bs = *(const short8*)(wr + kk * 32);
            short8 bd = *(const short8*)(wr + 128 + kk * 32);
            accs[nb] = __builtin_amdgcn_mfma_f32_16x16x32_bf16(a[kk], bs, accs[nb], 0, 0, 0);
            accd[nb] = __builtin_amdgcn_mfma_f32_16x16x32_bf16(a[kk], bd, accd[nb], 0, 0, 0);
        }
    }
    {
        const u16* wr = nw + (size_t)r15 * HID + kg;
        #pragma unroll
        for (int kk = 0; kk < 4; ++kk) {
            short8 bv = *(const short8*)(wr + kk * 32);
            accn = __builtin_amdgcn_mfma_f32_16x16x32_bf16(a[kk], bv, accn, 0, 0, 0);
        }
    }

    const int ob = blockIdx.x * 64 + wid * 16 + (lane >> 4) * 4;
    #pragma unroll
    for (int nb = 0; nb < 4; ++nb) {
        const int col = nb * 16 + r15;
        #pragma unroll
        for (int r = 0; r < 4; ++r) {
            y[(size_t)(ob + r) * 128 + col] = f2bf(accs[nb][r]);
            y[(size_t)(ob + r) * 128 + 64 + col] = f2bf(accd[nb][r]);
        }
    }
    const float bn = bf2f(nbias[r15]);
    #pragma unroll
    for (int r = 0; r < 4; ++r)
        node_out[(size_t)(ob + r) * NCLS + r15] = accn[r] + bn;
}

// ---------------------------------------------------------------------------
// edge output: out[e][c] = y[src[e]][c] + y[dst[e]][64+c] + eb[c]  (y bf16)
// ---------------------------------------------------------------------------
__global__ __launch_bounds__(256) void k_eout(
    const u16* __restrict__ y, const int* __restrict__ src, const int* __restrict__ dst,
    const float* __restrict__ eb, float* __restrict__ out)
{
    const int t = blockIdx.x * 256 + threadIdx.x;
    const int e = t >> 2;
    const int qq = (t & 3) * 16;
    const int s = src[e], d = dst[e];
    const u16* ys = y + (size_t)s * 128 + qq;
    const u16* yd = y + (size_t)d * 128 + 64 + qq;
    const float* ebp = eb + qq;
    float* op = out + (size_t)e * 64 + qq;
    #pragma unroll
    for (int c = 0; c < 2; ++c) {
        short8 vs = *(const short8*)(ys + c * 8);
        short8 vd = *(const short8*)(yd + c * 8);
        #pragma unroll
        for (int h = 0; h < 2; ++h) {
            f32x4 vb = *(const f32x4*)(ebp + c * 8 + h * 4);
            f32x4 r;
            #pragma unroll
            for (int j = 0; j < 4; ++j)
                r[j] = bf2f((u16)vs[h * 4 + j]) + bf2f((u16)vd[h * 4 + j]) + vb[j];
            *(f32x4*)(op + c * 8 + h * 4) = r;
        }
    }
}

// ---------------------------------------------------------------------------
__global__ void k_motif(const u16* __restrict__ x2, const int* __restrict__ centers,
                        const u16* __restrict__ mw, const u16* __restrict__ mb,
                        float* __restrict__ out)
{
    __shared__ float xs[HID];
    const int c = blockIdx.x, m = threadIdx.x;
    if (m < HID) xs[m] = bf2f(x2[(size_t)centers[c] * HID + m]);
    __syncthreads();
    const u16* wr = mw + (size_t)m * HID;
    float acc = bf2f(mb[m]);
    #pragma unroll
    for (int k0 = 0; k0 < HID; k0 += 8) {
        short8 wv = *(const short8*)(wr + k0);
        #pragma unroll
        for (int j = 0; j < 8; ++j) acc += xs[k0 + j] * bf2f((u16)wv[j]);
    }
    out[(size_t)c * N_MOTIFS + m] = acc;
}

// ---------------------------------------------------------------------------
extern "C" void kernel_launch(void* const* d_in, const int* in_sizes, int n_in,
                              void* d_out, int out_size, void* d_ws, size_t ws_size,
                              hipStream_t stream)
{
    const float* node_emb = (const float*)d_in[0];
    const float* rel_emb  = (const float*)d_in[1];
    const float* lin_w    = (const float*)d_in[2];
    const float* lin_b    = (const float*)d_in[3];
    const float* conv1_w  = (const float*)d_in[4];
    const float* conv1_b  = (const float*)d_in[5];
    const float* conv2_w  = (const float*)d_in[6];
    const float* conv2_b  = (const float*)d_in[7];
    const float* edge_w   = (const float*)d_in[8];
    const float* edge_b   = (const float*)d_in[9];
    const float* motif_w  = (const float*)d_in[10];
    const float* motif_b  = (const float*)d_in[11];
    const float* node_w   = (const float*)d_in[12];
    const float* node_b   = (const float*)d_in[13];
    const int* node_ids = (const int*)d_in[14];
    const int* rel_ids  = (const int*)d_in[15];
    const int* centers  = (const int*)d_in[16];
    const int* src      = (const int*)d_in[17];             // edge_index[0]
    const int* dst      = ((const int*)d_in[17]) + N_EDGES; // edge_index[1]

    // workspace layout (~165 MB):
    char* ws = (char*)d_ws;
    float* rel_lin = (float*)ws;                                  // 32 KB
    u16*   wb      = (u16*)(ws + 32768);                          // 268 KB
    u16*   rel_bf  = (u16*)(ws + 393216);                         // 16 KB
    u16*   x0      = (u16*)(ws + 524288);                         // 51.2 MB
    u16*   x1      = (u16*)(ws + 524288 + 51200000);              // 51.2 MB
    u16*   y       = (u16*)(ws + 524288 + 2 * 51200000);          // 51.2 MB bf16
    char*  csr     = ws + 524288 + 3 * 51200000;
    int*   deg     = (int*)csr;                                   // 800000
    int*   cur     = (int*)(csr + 800000);                        // 800000
    int*   row_ptr = (int*)(csr + 1600000);                       // 800004
    int*   srcrid  = (int*)(csr + 2400032);                       // 2400000
    int*   bsum    = (int*)(csr + 4800032);                       // 1564
    u16*   x2      = x0;

    float* out_edge  = (float*)d_out;                            // [600000][64]
    float* out_motif = out_edge + (size_t)N_EDGES * 64;          // [256][512]
    float* out_node  = out_motif + (size_t)N_CENTERS * N_MOTIFS; // [200000][16]

    // msg scratch (600000 x 128 bf16 = 153.6 MB) aliases out_edge (153.6 MB):
    // dead before k_eout, which overwrites every element of out_edge.
    u16* msg = (u16*)d_out;

    k_pre<<<64 + (N_WB + 127) / 128, 128, 0, stream>>>(
        rel_emb, lin_w, lin_b, conv1_w, conv1_b, conv2_w, conv2_b,
        edge_w, edge_b, motif_w, motif_b, node_w, node_b, rel_lin, rel_bf, wb);
    hipMemsetAsync(deg, 0, 1600000, stream);   // deg + cur

    // CSR build
    k_hist<<<(N_EDGES + 255) / 256, 256, 0, stream>>>(dst, deg);
    k_scan1<<<NB_SCAN, 256, 0, stream>>>(deg, bsum);
    k_scan2<<<1, 512, 0, stream>>>(bsum, row_ptr);
    k_scan3<<<NB_SCAN, 256, 0, stream>>>(deg, bsum, row_ptr);
    k_fill<<<(N_EDGES + 255) / 256, 256, 0, stream>>>(src, dst, rel_ids, row_ptr, cur, srcrid);

    k_lin<<<N_NODES / 64, 256, 0, stream>>>(node_emb, node_ids, wb + O_LINW, wb + O_LINB, x0);

    // layer 1
    k_msg2<<<(N_EDGES * 4) / 256, 256, 0, stream>>>(x0, rel_bf, srcrid, msg);
    k_fuse2<<<N_NODES / 64, 256, 0, stream>>>(x0, msg, row_ptr,
                                              wb + O_C1W, wb + O_C1B, x1, 1);
    // layer 2
    k_msg2<<<(N_EDGES * 4) / 256, 256, 0, stream>>>(x1, rel_bf, srcrid, msg);
    k_fuse2<<<N_NODES / 64, 256, 0, stream>>>(x1, msg, row_ptr,
                                              wb + O_C2W, wb + O_C2B, x2, 0);

    k_heads<<<N_NODES / 64, 256, 0, stream>>>(x2, wb + O_EW, wb + O_NW, wb + O_NB, y, out_node);
    k_eout<<<(N_EDGES * 4) / 256, 256, 0, stream>>>(y, src, dst, edge_b, out_edge);
    k_motif<<<N_CENTERS, N_MOTIFS, 0, stream>>>(x2, centers, wb + O_MW, wb + O_MB, out_motif);
}

// Round 11
// 497.849 us; speedup vs baseline: 1.1217x; 1.1217x over previous
//
#include <hip/hip_runtime.h>
#include <hip/hip_bf16.h>

#define N_NODES 200000
#define N_EDGES 600000
#define EMB 128
#define HID 128
#define N_RELS 64
#define N_MOTIFS 512
#define N_CENTERS 256
#define NCLS 16

#define SCAN_C 512
#define NB_SCAN ((N_NODES + SCAN_C - 1) / SCAN_C)   // 391

typedef unsigned short u16;
typedef __attribute__((ext_vector_type(8))) short short8;   // 8 x bf16
typedef __attribute__((ext_vector_type(4))) float f32x4;

__device__ __forceinline__ float bf2f(u16 u) {
    unsigned int i = ((unsigned int)u) << 16;
    float f; __builtin_memcpy(&f, &i, 4); return f;
}
__device__ __forceinline__ u16 f2bf(float f) {
    unsigned int x; __builtin_memcpy(&x, &f, 4);
    x += 0x7fffu + ((x >> 16) & 1u);          // RNE
    return (u16)(x >> 16);
}

// bf16 weight-table offsets (elements) inside ws
#define O_LINW   0
#define O_LINB   16384
#define O_C1W    16512
#define O_C1B    32896
#define O_C2W    33024
#define O_C2B    49408
#define O_EW     49536
#define O_EB     65920
#define O_MW     65984
#define O_MB     131520
#define O_NW     132032
#define O_NB     134080
#define N_WB     134096

// ---------------------------------------------------------------------------
// merged prologue: blocks 0..63 compute rel_lin (f32 + bf16); rest convert
// the 12 weight arrays to the bf16 table. 128 threads/block.
// ---------------------------------------------------------------------------
__global__ void k_pre(const float* __restrict__ rel_emb,
                      const float* __restrict__ lw, const float* __restrict__ lb,
                      const float* __restrict__ c1w, const float* __restrict__ c1b,
                      const float* __restrict__ c2w, const float* __restrict__ c2b,
                      const float* __restrict__ ew, const float* __restrict__ eb,
                      const float* __restrict__ mw, const float* __restrict__ mb,
                      const float* __restrict__ nw, const float* __restrict__ nb,
                      float* __restrict__ rel_lin, u16* __restrict__ rel_bf,
                      u16* __restrict__ wb)
{
    if (blockIdx.x < 64) {
        __shared__ float e[EMB];
        const int r = blockIdx.x, h = threadIdx.x;
        e[h] = rel_emb[r * EMB + h];
        __syncthreads();
        const float* wr = lw + (size_t)h * EMB;
        float acc = lb[h];
        #pragma unroll
        for (int k0 = 0; k0 < EMB; k0 += 4) {
            f32x4 wv = *(const f32x4*)(wr + k0);
            #pragma unroll
            for (int j = 0; j < 4; ++j) acc += e[k0 + j] * wv[j];
        }
        rel_lin[r * HID + h] = acc;
        rel_bf[r * HID + h] = f2bf(acc);
        return;
    }
    const int t = (blockIdx.x - 64) * 128 + threadIdx.x;
    if (t >= N_WB) return;
    float v;
    if      (t < O_LINB) v = lw[t - O_LINW];
    else if (t < O_C1W)  v = lb[t - O_LINB];
    else if (t < O_C1B)  v = c1w[t - O_C1W];
    else if (t < O_C2W)  v = c1b[t - O_C1B];
    else if (t < O_C2B)  v = c2w[t - O_C2W];
    else if (t < O_EW)   v = c2b[t - O_C2B];
    else if (t < O_EB)   v = ew[t - O_EW];
    else if (t < O_MW)   v = eb[t - O_EB];
    else if (t < O_MB)   v = mw[t - O_MW];
    else if (t < O_NW)   v = mb[t - O_MB];
    else if (t < O_NB)   v = nw[t - O_NW];
    else                 v = nb[t - O_NB];
    wb[t] = f2bf(v);
}

// ---------------------------------------------------------------------------
// CSR build
// ---------------------------------------------------------------------------
__global__ void k_hist(const int* __restrict__ dst, int* __restrict__ deg)
{
    const int e = blockIdx.x * 256 + threadIdx.x;
    if (e < N_EDGES) atomicAdd(&deg[dst[e]], 1);
}

__global__ void k_scan1(const int* __restrict__ deg, int* __restrict__ bsum)
{
    __shared__ int sd[256];
    const int t = threadIdx.x, base = blockIdx.x * SCAN_C;
    int v = 0;
    int i0 = base + t, i1 = base + 256 + t;
    if (i0 < N_NODES) v += deg[i0];
    if (i1 < N_NODES) v += deg[i1];
    sd[t] = v; __syncthreads();
    for (int s = 128; s > 0; s >>= 1) {
        if (t < s) sd[t] += sd[t + s];
        __syncthreads();
    }
    if (t == 0) bsum[blockIdx.x] = sd[0];
}

__global__ void k_scan2(int* __restrict__ bsum, int* __restrict__ row_ptr)
{
    __shared__ int sh[512];
    const int t = threadIdx.x;
    int v = (t < NB_SCAN) ? bsum[t] : 0;
    sh[t] = v;
    for (int off = 1; off < 512; off <<= 1) {
        __syncthreads();
        int a = (t >= off) ? sh[t - off] : 0;
        __syncthreads();
        sh[t] += a;
    }
    __syncthreads();
    if (t < NB_SCAN) bsum[t] = sh[t] - v;         // exclusive
    if (t == 511) row_ptr[N_NODES] = sh[511];     // total = E
}

__global__ void k_scan3(const int* __restrict__ deg, const int* __restrict__ bsum,
                        int* __restrict__ row_ptr)
{
    __shared__ int sh[256];
    const int t = threadIdx.x, base = blockIdx.x * SCAN_C;
    const int i0 = base + 2 * t, i1 = i0 + 1;
    int d0 = (i0 < N_NODES) ? deg[i0] : 0;
    int d1 = (i1 < N_NODES) ? deg[i1] : 0;
    int p = d0 + d1;
    sh[t] = p;
    for (int off = 1; off < 256; off <<= 1) {
        __syncthreads();
        int a = (t >= off) ? sh[t - off] : 0;
        __syncthreads();
        sh[t] += a;
    }
    __syncthreads();
    const int off = bsum[blockIdx.x] + sh[t] - p;  // exclusive within block
    if (i0 < N_NODES) row_ptr[i0] = off;
    if (i1 < N_NODES) row_ptr[i1] = off + d0;
}

__global__ void k_fill(const int* __restrict__ src, const int* __restrict__ dst,
                       const int* __restrict__ rid, const int* __restrict__ row_ptr,
                       int* __restrict__ cur, int* __restrict__ srcrid)
{
    const int e = blockIdx.x * 256 + threadIdx.x;
    if (e >= N_EDGES) return;
    const int d = dst[e];
    const int pos = row_ptr[d] + atomicAdd(&cur[d], 1);
    srcrid[pos] = src[e] * 64 + rid[e];
}

// ---------------------------------------------------------------------------
// x0 = bf16( node_emb[ids] @ lin_w^T + lin_b )
// ---------------------------------------------------------------------------
__global__ __launch_bounds__(256) void k_lin(
    const float* __restrict__ emb, const int* __restrict__ ids,
    const u16* __restrict__ w, const u16* __restrict__ bias,
    u16* __restrict__ out)
{
    const int wid = threadIdx.x >> 6, lane = threadIdx.x & 63;
    const int r15 = lane & 15, kg = (lane >> 4) * 8;
    const int arow = blockIdx.x * 64 + wid * 16 + r15;
    const int srow = ids[arow];
    const float* ar = emb + (size_t)srow * EMB + kg;
    short8 a[4];
    #pragma unroll
    for (int kk = 0; kk < 4; ++kk) {
        f32x4 a0 = *(const f32x4*)(ar + kk * 32);
        f32x4 a1 = *(const f32x4*)(ar + kk * 32 + 4);
        short8 t;
        #pragma unroll
        for (int j = 0; j < 4; ++j) { t[j] = (short)f2bf(a0[j]); t[4 + j] = (short)f2bf(a1[j]); }
        a[kk] = t;
    }
    f32x4 acc[8];
    #pragma unroll
    for (int nb = 0; nb < 8; ++nb) acc[nb] = (f32x4){0.f, 0.f, 0.f, 0.f};
    #pragma unroll
    for (int nb = 0; nb < 8; ++nb) {
        const u16* wr = w + (size_t)(nb * 16 + r15) * EMB + kg;
        #pragma unroll
        for (int kk = 0; kk < 4; ++kk) {
            short8 bv = *(const short8*)(wr + kk * 32);
            acc[nb] = __builtin_amdgcn_mfma_f32_16x16x32_bf16(a[kk], bv, acc[nb], 0, 0, 0);
        }
    }
    const int ob = blockIdx.x * 64 + wid * 16 + (lane >> 4) * 4;
    #pragma unroll
    for (int nb = 0; nb < 8; ++nb) {
        const int col = nb * 16 + r15;
        const float bn = bf2f(bias[col]);
        #pragma unroll
        for (int r = 0; r < 4; ++r)
            out[(size_t)(ob + r) * HID + col] = f2bf(acc[nb][r] + bn);
    }
}

// ---------------------------------------------------------------------------
// FUSED agg + conv, low-VGPR (round 11):
//   128 threads = 16 nodes x 8 threads; each thread aggregates 16 channels
//   (acc[16]) -> small LDS atile [16][136] -> 2 waves split the MFMA conv
//   by output-column halves. rel table = bf16 global (16 KB, L1-resident).
// ---------------------------------------------------------------------------
#define ALD 136
__global__ __launch_bounds__(128) void k_fuse(
    const u16* __restrict__ x, const u16* __restrict__ relb,
    const int* __restrict__ row_ptr, const int* __restrict__ srcrid,
    const u16* __restrict__ w, const u16* __restrict__ bias,
    u16* __restrict__ out, const int do_relu)
{
    __shared__ u16 atile[16 * ALD];     // 4.4 KB

    // ---- phase 1: gather-aggregate, 8 threads/node, 16 ch/thread ----
    const int nl = threadIdx.x & 15;              // local node 0..15
    const int g  = threadIdx.x >> 4;              // channel group 0..7
    const int ch = g * 16;
    const int n = blockIdx.x * 16 + nl;
    const int pbeg = row_ptr[n], pend = row_ptr[n + 1];

    float acc[16];
    #pragma unroll
    for (int j = 0; j < 16; ++j) acc[j] = 0.f;

    int p = pbeg;
    for (; p + 2 <= pend; p += 2) {
        const int v0 = srcrid[p], v1 = srcrid[p + 1];
        const int s0 = v0 >> 6, r0 = v0 & 63;
        const int s1 = v1 >> 6, r1 = v1 & 63;
        const u16* xp0 = x + (size_t)s0 * HID + ch;
        const u16* xp1 = x + (size_t)s1 * HID + ch;
        const u16* rp0 = relb + r0 * HID + ch;
        const u16* rp1 = relb + r1 * HID + ch;
        short8 xv0[2], xv1[2], rv0[2], rv1[2];
        #pragma unroll
        for (int c = 0; c < 2; ++c) {
            xv0[c] = *(const short8*)(xp0 + c * 8);
            xv1[c] = *(const short8*)(xp1 + c * 8);
            rv0[c] = *(const short8*)(rp0 + c * 8);
            rv1[c] = *(const short8*)(rp1 + c * 8);
        }
        #pragma unroll
        for (int c = 0; c < 2; ++c)
            #pragma unroll
            for (int j = 0; j < 8; ++j) {
                acc[c * 8 + j] += fmaxf(bf2f((u16)xv0[c][j]) + bf2f((u16)rv0[c][j]), 0.f);
                acc[c * 8 + j] += fmaxf(bf2f((u16)xv1[c][j]) + bf2f((u16)rv1[c][j]), 0.f);
            }
    }
    if (p < pend) {
        const int v = srcrid[p];
        const int s = v >> 6, r = v & 63;
        const u16* xp = x + (size_t)s * HID + ch;
        const u16* rp = relb + r * HID + ch;
        #pragma unroll
        for (int c = 0; c < 2; ++c) {
            short8 xv = *(const short8*)(xp + c * 8);
            short8 rv = *(const short8*)(rp + c * 8);
            #pragma unroll
            for (int j = 0; j < 8; ++j)
                acc[c * 8 + j] += fmaxf(bf2f((u16)xv[j]) + bf2f((u16)rv[j]), 0.f);
        }
    }
    {   // add own x row, cvt bf16, stash in atile
        const u16* xp = x + (size_t)n * HID + ch;
        #pragma unroll
        for (int c = 0; c < 2; ++c) {
            short8 xv = *(const short8*)(xp + c * 8);
            short8 t;
            #pragma unroll
            for (int j = 0; j < 8; ++j) t[j] = (short)f2bf(acc[c * 8 + j] + bf2f((u16)xv[j]));
            *(short8*)(&atile[nl * ALD + ch + c * 8]) = t;
        }
    }
    __syncthreads();

    // ---- phase 2: MFMA conv; wave wid handles output cols [wid*64, wid*64+64) ----
    const int wid = threadIdx.x >> 6, lane = threadIdx.x & 63;
    const int r15 = lane & 15, kg = (lane >> 4) * 8;
    short8 a[4];
    #pragma unroll
    for (int kk = 0; kk < 4; ++kk)
        a[kk] = *(const short8*)(&atile[r15 * ALD + kg + kk * 32]);

    f32x4 accm[4];
    #pragma unroll
    for (int nb = 0; nb < 4; ++nb) accm[nb] = (f32x4){0.f, 0.f, 0.f, 0.f};
    #pragma unroll
    for (int nb = 0; nb < 4; ++nb) {
        const u16* wr = w + (size_t)(wid * 64 + nb * 16 + r15) * HID + kg;
        #pragma unroll
        for (int kk = 0; kk < 4; ++kk) {
            short8 bv = *(const short8*)(wr + kk * 32);
            accm[nb] = __builtin_amdgcn_mfma_f32_16x16x32_bf16(a[kk], bv, accm[nb], 0, 0, 0);
        }
    }
    const int ob = blockIdx.x * 16 + (lane >> 4) * 4;
    #pragma unroll
    for (int nb = 0; nb < 4; ++nb) {
        const int col = wid * 64 + nb * 16 + r15;
        const float bn = bf2f(bias[col]);
        #pragma unroll
        for (int r = 0; r < 4; ++r) {
            float v = accm[nb][r] + bn;
            if (do_relu) v = fmaxf(v, 0.f);
            out[(size_t)(ob + r) * HID + col] = f2bf(v);
        }
    }
}

// ---------------------------------------------------------------------------
// heads precompute:  y (bf16) [n][0:64]=x2.ew_src, [64:128]=x2.ew_dst;
//                    node_out[n] = x2[n].nw + nb  (f32)
// ---------------------------------------------------------------------------
__global__ __launch_bounds__(256) void k_heads(
    const u16* __restrict__ x2, const u16* __restrict__ ew,
    const u16* __restrict__ nw, const u16* __restrict__ nbias,
    u16* __restrict__ y, float* __restrict__ node_out)
{
    const int wid = threadIdx.x >> 6, lane = threadIdx.x & 63;
    const int r15 = lane & 15, kg = (lane >> 4) * 8;
    const int arow = blockIdx.x * 64 + wid * 16 + r15;
    const u16* xr = x2 + (size_t)arow * HID + kg;
    short8 a[4];
    #pragma unroll
    for (int kk = 0; kk < 4; ++kk) a[kk] = *(const short8*)(xr + kk * 32);

    f32x4 accs[4], accd[4], accn;
    #pragma unroll
    for (int nb = 0; nb < 4; ++nb) {
        accs[nb] = (f32x4){0.f, 0.f, 0.f, 0.f};
        accd[nb] = (f32x4){0.f, 0.f, 0.f, 0.f};
    }
    accn = (f32x4){0.f, 0.f, 0.f, 0.f};

    #pragma unroll
    for (int nb = 0; nb < 4; ++nb) {
        const u16* wr = ew + (size_t)(nb * 16 + r15) * 256 + kg;
        #pragma unroll
        for (int kk = 0; kk < 4; ++kk) {
            short8 bs = *(const short8*)(wr + kk * 32);
            short8 bd = *(const short8*)(wr + 128 + kk * 32);
            accs[nb] = __builtin_amdgcn_mfma_f32_16x16x32_bf16(a[kk], bs, accs[nb], 0, 0, 0);
            accd[nb] = __builtin_amdgcn_mfma_f32_16x16x32_bf16(a[kk], bd, accd[nb], 0, 0, 0);
        }
    }
    {
        const u16* wr = nw + (size_t)r15 * HID + kg;
        #pragma unroll
        for (int kk = 0; kk < 4; ++kk) {
            short8 bv = *(const short8*)(wr + kk * 32);
            accn = __builtin_amdgcn_mfma_f32_16x16x32_bf16(a[kk], bv, accn, 0, 0, 0);
        }
    }

    const int ob = blockIdx.x * 64 + wid * 16 + (lane >> 4) * 4;
    #pragma unroll
    for (int nb = 0; nb < 4; ++nb) {
        const int col = nb * 16 + r15;
        #pragma unroll
        for (int r = 0; r < 4; ++r) {
            y[(size_t)(ob + r) * 128 + col] = f2bf(accs[nb][r]);
            y[(size_t)(ob + r) * 128 + 64 + col] = f2bf(accd[nb][r]);
        }
    }
    const float bn = bf2f(nbias[r15]);
    #pragma unroll
    for (int r = 0; r < 4; ++r)
        node_out[(size_t)(ob + r) * NCLS + r15] = accn[r] + bn;
}

// ---------------------------------------------------------------------------
// edge output: out[e][c] = y[src[e]][c] + y[dst[e]][64+c] + eb[c]  (y bf16)
// ---------------------------------------------------------------------------
__global__ __launch_bounds__(256) void k_eout(
    const u16* __restrict__ y, const int* __restrict__ src, const int* __restrict__ dst,
    const float* __restrict__ eb, float* __restrict__ out)
{
    const int t = blockIdx.x * 256 + threadIdx.x;
    const int e = t >> 2;
    const int qq = (t & 3) * 16;
    const int s = src[e], d = dst[e];
    const u16* ys = y + (size_t)s * 128 + qq;
    const u16* yd = y + (size_t)d * 128 + 64 + qq;
    const float* ebp = eb + qq;
    float* op = out + (size_t)e * 64 + qq;
    #pragma unroll
    for (int c = 0; c < 2; ++c) {
        short8 vs = *(const short8*)(ys + c * 8);
        short8 vd = *(const short8*)(yd + c * 8);
        #pragma unroll
        for (int h = 0; h < 2; ++h) {
            f32x4 vb = *(const f32x4*)(ebp + c * 8 + h * 4);
            f32x4 r;
            #pragma unroll
            for (int j = 0; j < 4; ++j)
                r[j] = bf2f((u16)vs[h * 4 + j]) + bf2f((u16)vd[h * 4 + j]) + vb[j];
            *(f32x4*)(op + c * 8 + h * 4) = r;
        }
    }
}

// ---------------------------------------------------------------------------
__global__ void k_motif(const u16* __restrict__ x2, const int* __restrict__ centers,
                        const u16* __restrict__ mw, const u16* __restrict__ mb,
                        float* __restrict__ out)
{
    __shared__ float xs[HID];
    const int c = blockIdx.x, m = threadIdx.x;
    if (m < HID) xs[m] = bf2f(x2[(size_t)centers[c] * HID + m]);
    __syncthreads();
    const u16* wr = mw + (size_t)m * HID;
    float acc = bf2f(mb[m]);
    #pragma unroll
    for (int k0 = 0; k0 < HID; k0 += 8) {
        short8 wv = *(const short8*)(wr + k0);
        #pragma unroll
        for (int j = 0; j < 8; ++j) acc += xs[k0 + j] * bf2f((u16)wv[j]);
    }
    out[(size_t)c * N_MOTIFS + m] = acc;
}

// ---------------------------------------------------------------------------
extern "C" void kernel_launch(void* const* d_in, const int* in_sizes, int n_in,
                              void* d_out, int out_size, void* d_ws, size_t ws_size,
                              hipStream_t stream)
{
    const float* node_emb = (const float*)d_in[0];
    const float* rel_emb  = (const float*)d_in[1];
    const float* lin_w    = (const float*)d_in[2];
    const float* lin_b    = (const float*)d_in[3];
    const float* conv1_w  = (const float*)d_in[4];
    const float* conv1_b  = (const float*)d_in[5];
    const float* conv2_w  = (const float*)d_in[6];
    const float* conv2_b  = (const float*)d_in[7];
    const float* edge_w   = (const float*)d_in[8];
    const float* edge_b   = (const float*)d_in[9];
    const float* motif_w  = (const float*)d_in[10];
    const float* motif_b  = (const float*)d_in[11];
    const float* node_w   = (const float*)d_in[12];
    const float* node_b   = (const float*)d_in[13];
    const int* node_ids = (const int*)d_in[14];
    const int* rel_ids  = (const int*)d_in[15];
    const int* centers  = (const int*)d_in[16];
    const int* src      = (const int*)d_in[17];             // edge_index[0]
    const int* dst      = ((const int*)d_in[17]) + N_EDGES; // edge_index[1]

    // workspace layout (~160 MB):
    char* ws = (char*)d_ws;
    float* rel_lin = (float*)ws;                                  // 32 KB
    u16*   wb      = (u16*)(ws + 32768);                          // 268 KB
    u16*   rel_bf  = (u16*)(ws + 393216);                         // 16 KB
    u16*   x0      = (u16*)(ws + 524288);                         // 51.2 MB
    u16*   x1      = (u16*)(ws + 524288 + 51200000);              // 51.2 MB
    u16*   y       = (u16*)(ws + 524288 + 2 * 51200000);          // 51.2 MB bf16
    char*  csr     = ws + 524288 + 3 * 51200000;
    int*   deg     = (int*)csr;                                   // 800000
    int*   cur     = (int*)(csr + 800000);                        // 800000
    int*   row_ptr = (int*)(csr + 1600000);                       // 800004
    int*   srcrid  = (int*)(csr + 2400032);                       // 2400000
    int*   bsum    = (int*)(csr + 4800032);                       // 1564
    u16*   x2      = x0;

    float* out_edge  = (float*)d_out;                            // [600000][64]
    float* out_motif = out_edge + (size_t)N_EDGES * 64;          // [256][512]
    float* out_node  = out_motif + (size_t)N_CENTERS * N_MOTIFS; // [200000][16]

    k_pre<<<64 + (N_WB + 127) / 128, 128, 0, stream>>>(
        rel_emb, lin_w, lin_b, conv1_w, conv1_b, conv2_w, conv2_b,
        edge_w, edge_b, motif_w, motif_b, node_w, node_b, rel_lin, rel_bf, wb);
    hipMemsetAsync(deg, 0, 1600000, stream);   // deg + cur

    // CSR build
    k_hist<<<(N_EDGES + 255) / 256, 256, 0, stream>>>(dst, deg);
    k_scan1<<<NB_SCAN, 256, 0, stream>>>(deg, bsum);
    k_scan2<<<1, 512, 0, stream>>>(bsum, row_ptr);
    k_scan3<<<NB_SCAN, 256, 0, stream>>>(deg, bsum, row_ptr);
    k_fill<<<(N_EDGES + 255) / 256, 256, 0, stream>>>(src, dst, rel_ids, row_ptr, cur, srcrid);

    k_lin<<<N_NODES / 64, 256, 0, stream>>>(node_emb, node_ids, wb + O_LINW, wb + O_LINB, x0);

    k_fuse<<<N_NODES / 16, 128, 0, stream>>>(x0, rel_bf, row_ptr, srcrid,
                                             wb + O_C1W, wb + O_C1B, x1, 1);
    k_fuse<<<N_NODES / 16, 128, 0, stream>>>(x1, rel_bf, row_ptr, srcrid,
                                             wb + O_C2W, wb + O_C2B, x2, 0);

    k_heads<<<N_NODES / 64, 256, 0, stream>>>(x2, wb + O_EW, wb + O_NW, wb + O_NB, y, out_node);
    k_eout<<<(N_EDGES * 4) / 256, 256, 0, stream>>>(y, src, dst, edge_b, out_edge);
    k_motif<<<N_CENTERS, N_MOTIFS, 0, stream>>>(x2, centers, wb + O_MW, wb + O_MB, out_motif);
}

// Round 12
// 453.234 us; speedup vs baseline: 1.2321x; 1.0984x over previous
//
#include <hip/hip_runtime.h>
#include <hip/hip_bf16.h>

#define N_NODES 200000
#define N_EDGES 600000
#define EMB 128
#define HID 128
#define N_RELS 64
#define N_MOTIFS 512
#define N_CENTERS 256
#define NCLS 16

#define SCAN_C 512
#define NB_SCAN ((N_NODES + SCAN_C - 1) / SCAN_C)   // 391

typedef unsigned short u16;
typedef __attribute__((ext_vector_type(8))) short short8;   // 8 x bf16
typedef __attribute__((ext_vector_type(4))) float f32x4;

__device__ __forceinline__ float bf2f(u16 u) {
    unsigned int i = ((unsigned int)u) << 16;
    float f; __builtin_memcpy(&f, &i, 4); return f;
}
__device__ __forceinline__ u16 f2bf(float f) {
    unsigned int x; __builtin_memcpy(&x, &f, 4);
    x += 0x7fffu + ((x >> 16) & 1u);          // RNE
    return (u16)(x >> 16);
}

// bf16 weight-table offsets (elements) inside ws
#define O_LINW   0
#define O_LINB   16384
#define O_C1W    16512
#define O_C1B    32896
#define O_C2W    33024
#define O_C2B    49408
#define O_EW     49536
#define O_EB     65920
#define O_MW     65984
#define O_MB     131520
#define O_NW     132032
#define O_NB     134080
#define N_WB     134096

// ---------------------------------------------------------------------------
// merged prologue: blocks 0..63 compute rel_lin (f32 + bf16); rest convert
// the 12 weight arrays to the bf16 table. 128 threads/block.
// ---------------------------------------------------------------------------
__global__ void k_pre(const float* __restrict__ rel_emb,
                      const float* __restrict__ lw, const float* __restrict__ lb,
                      const float* __restrict__ c1w, const float* __restrict__ c1b,
                      const float* __restrict__ c2w, const float* __restrict__ c2b,
                      const float* __restrict__ ew, const float* __restrict__ eb,
                      const float* __restrict__ mw, const float* __restrict__ mb,
                      const float* __restrict__ nw, const float* __restrict__ nb,
                      float* __restrict__ rel_lin, u16* __restrict__ rel_bf,
                      u16* __restrict__ wb)
{
    if (blockIdx.x < 64) {
        __shared__ float e[EMB];
        const int r = blockIdx.x, h = threadIdx.x;
        e[h] = rel_emb[r * EMB + h];
        __syncthreads();
        const float* wr = lw + (size_t)h * EMB;
        float acc = lb[h];
        #pragma unroll
        for (int k0 = 0; k0 < EMB; k0 += 4) {
            f32x4 wv = *(const f32x4*)(wr + k0);
            #pragma unroll
            for (int j = 0; j < 4; ++j) acc += e[k0 + j] * wv[j];
        }
        rel_lin[r * HID + h] = acc;
        rel_bf[r * HID + h] = f2bf(acc);
        return;
    }
    const int t = (blockIdx.x - 64) * 128 + threadIdx.x;
    if (t >= N_WB) return;
    float v;
    if      (t < O_LINB) v = lw[t - O_LINW];
    else if (t < O_C1W)  v = lb[t - O_LINB];
    else if (t < O_C1B)  v = c1w[t - O_C1W];
    else if (t < O_C2W)  v = c1b[t - O_C1B];
    else if (t < O_C2B)  v = c2w[t - O_C2W];
    else if (t < O_EW)   v = c2b[t - O_C2B];
    else if (t < O_EB)   v = ew[t - O_EW];
    else if (t < O_MW)   v = eb[t - O_EB];
    else if (t < O_MB)   v = mw[t - O_MW];
    else if (t < O_NW)   v = mb[t - O_MB];
    else if (t < O_NB)   v = nw[t - O_NW];
    else                 v = nb[t - O_NB];
    wb[t] = f2bf(v);
}

// ---------------------------------------------------------------------------
// CSR build
// ---------------------------------------------------------------------------
__global__ void k_hist(const int* __restrict__ dst, int* __restrict__ deg)
{
    const int e = blockIdx.x * 256 + threadIdx.x;
    if (e < N_EDGES) atomicAdd(&deg[dst[e]], 1);
}

__global__ void k_scan1(const int* __restrict__ deg, int* __restrict__ bsum)
{
    __shared__ int sd[256];
    const int t = threadIdx.x, base = blockIdx.x * SCAN_C;
    int v = 0;
    int i0 = base + t, i1 = base + 256 + t;
    if (i0 < N_NODES) v += deg[i0];
    if (i1 < N_NODES) v += deg[i1];
    sd[t] = v; __syncthreads();
    for (int s = 128; s > 0; s >>= 1) {
        if (t < s) sd[t] += sd[t + s];
        __syncthreads();
    }
    if (t == 0) bsum[blockIdx.x] = sd[0];
}

__global__ void k_scan2(int* __restrict__ bsum, int* __restrict__ row_ptr)
{
    __shared__ int sh[512];
    const int t = threadIdx.x;
    int v = (t < NB_SCAN) ? bsum[t] : 0;
    sh[t] = v;
    for (int off = 1; off < 512; off <<= 1) {
        __syncthreads();
        int a = (t >= off) ? sh[t - off] : 0;
        __syncthreads();
        sh[t] += a;
    }
    __syncthreads();
    if (t < NB_SCAN) bsum[t] = sh[t] - v;         // exclusive
    if (t == 511) row_ptr[N_NODES] = sh[511];     // total = E
}

__global__ void k_scan3(const int* __restrict__ deg, const int* __restrict__ bsum,
                        int* __restrict__ row_ptr)
{
    __shared__ int sh[256];
    const int t = threadIdx.x, base = blockIdx.x * SCAN_C;
    const int i0 = base + 2 * t, i1 = i0 + 1;
    int d0 = (i0 < N_NODES) ? deg[i0] : 0;
    int d1 = (i1 < N_NODES) ? deg[i1] : 0;
    int p = d0 + d1;
    sh[t] = p;
    for (int off = 1; off < 256; off <<= 1) {
        __syncthreads();
        int a = (t >= off) ? sh[t - off] : 0;
        __syncthreads();
        sh[t] += a;
    }
    __syncthreads();
    const int off = bsum[blockIdx.x] + sh[t] - p;  // exclusive within block
    if (i0 < N_NODES) row_ptr[i0] = off;
    if (i1 < N_NODES) row_ptr[i1] = off + d0;
}

__global__ void k_fill(const int* __restrict__ src, const int* __restrict__ dst,
                       const int* __restrict__ rid, const int* __restrict__ row_ptr,
                       int* __restrict__ cur, int* __restrict__ srcrid)
{
    const int e = blockIdx.x * 256 + threadIdx.x;
    if (e >= N_EDGES) return;
    const int d = dst[e];
    const int pos = row_ptr[d] + atomicAdd(&cur[d], 1);
    srcrid[pos] = src[e] * 64 + rid[e];
}

// ---------------------------------------------------------------------------
// x0 = bf16( node_emb[ids] @ lin_w^T + lin_b )
// ---------------------------------------------------------------------------
__global__ __launch_bounds__(256) void k_lin(
    const float* __restrict__ emb, const int* __restrict__ ids,
    const u16* __restrict__ w, const u16* __restrict__ bias,
    u16* __restrict__ out)
{
    const int wid = threadIdx.x >> 6, lane = threadIdx.x & 63;
    const int r15 = lane & 15, kg = (lane >> 4) * 8;
    const int arow = blockIdx.x * 64 + wid * 16 + r15;
    const int srow = ids[arow];
    const float* ar = emb + (size_t)srow * EMB + kg;
    short8 a[4];
    #pragma unroll
    for (int kk = 0; kk < 4; ++kk) {
        f32x4 a0 = *(const f32x4*)(ar + kk * 32);
        f32x4 a1 = *(const f32x4*)(ar + kk * 32 + 4);
        short8 t;
        #pragma unroll
        for (int j = 0; j < 4; ++j) { t[j] = (short)f2bf(a0[j]); t[4 + j] = (short)f2bf(a1[j]); }
        a[kk] = t;
    }
    f32x4 acc[8];
    #pragma unroll
    for (int nb = 0; nb < 8; ++nb) acc[nb] = (f32x4){0.f, 0.f, 0.f, 0.f};
    #pragma unroll
    for (int nb = 0; nb < 8; ++nb) {
        const u16* wr = w + (size_t)(nb * 16 + r15) * EMB + kg;
        #pragma unroll
        for (int kk = 0; kk < 4; ++kk) {
            short8 bv = *(const short8*)(wr + kk * 32);
            acc[nb] = __builtin_amdgcn_mfma_f32_16x16x32_bf16(a[kk], bv, acc[nb], 0, 0, 0);
        }
    }
    const int ob = blockIdx.x * 64 + wid * 16 + (lane >> 4) * 4;
    #pragma unroll
    for (int nb = 0; nb < 8; ++nb) {
        const int col = nb * 16 + r15;
        const float bn = bf2f(bias[col]);
        #pragma unroll
        for (int r = 0; r < 4; ++r)
            out[(size_t)(ob + r) * HID + col] = f2bf(acc[nb][r] + bn);
    }
}

// ---------------------------------------------------------------------------
// FUSED agg + conv, frag-native (r6 structure, best known):
//   thread owns MFMA A-frag slots: node row = wid*16+(lane&15),
//   channels kg + kk*32 + j  (kg=(lane>>4)*8).  Aggregation acc[] IS the
//   A-fragment -> no atile LDS, no mid-kernel barrier.
//   rel table in LDS as bf16, XOR-swizzled 16B chunks; staged from rel_bf.
// ---------------------------------------------------------------------------
__global__ __launch_bounds__(256) void k_fuse(
    const u16* __restrict__ x, const u16* __restrict__ rel_src,
    const int* __restrict__ row_ptr, const int* __restrict__ srcrid,
    const u16* __restrict__ w, const u16* __restrict__ bias,
    u16* __restrict__ out, const int do_relu)
{
    __shared__ u16 rel[N_RELS * 128];   // 16 KB, swizzled
    {   // stage: 256 thr x 4 chunks = 1024 chunks of 8 bf16 (16B each)
        const int r = threadIdx.x >> 2;
        #pragma unroll
        for (int k = 0; k < 4; ++k) {
            const int ch = (threadIdx.x & 3) * 4 + k;       // 0..15
            short8 t = *(const short8*)(rel_src + r * HID + ch * 8);
            *(short8*)(&rel[r * 128 + ((ch ^ (r & 7)) * 8)]) = t;
        }
    }
    __syncthreads();

    const int wid = threadIdx.x >> 6, lane = threadIdx.x & 63;
    const int r15 = lane & 15;
    const int kq  = lane >> 4;          // k-quadrant 0..3
    const int kg  = kq * 8;
    const int n = blockIdx.x * 64 + wid * 16 + r15;
    const int pbeg = row_ptr[n], pend = row_ptr[n + 1];

    float acc[32];
    #pragma unroll
    for (int j = 0; j < 32; ++j) acc[j] = 0.f;

    int p = pbeg;
    for (; p + 2 <= pend; p += 2) {
        const int v0 = srcrid[p], v1 = srcrid[p + 1];
        const int s0 = v0 >> 6, r0 = v0 & 63;
        const int s1 = v1 >> 6, r1 = v1 & 63;
        const u16* xp0 = x + (size_t)s0 * HID + kg;
        const u16* xp1 = x + (size_t)s1 * HID + kg;
        short8 xv0[4], xv1[4], rv0[4], rv1[4];
        #pragma unroll
        for (int kk = 0; kk < 4; ++kk) {
            xv0[kk] = *(const short8*)(xp0 + kk * 32);
            xv1[kk] = *(const short8*)(xp1 + kk * 32);
            rv0[kk] = *(const short8*)(&rel[r0 * 128 + (((kq + kk * 4) ^ (r0 & 7)) * 8)]);
            rv1[kk] = *(const short8*)(&rel[r1 * 128 + (((kq + kk * 4) ^ (r1 & 7)) * 8)]);
        }
        #pragma unroll
        for (int kk = 0; kk < 4; ++kk)
            #pragma unroll
            for (int j = 0; j < 8; ++j) {
                acc[kk * 8 + j] += fmaxf(bf2f((u16)xv0[kk][j]) + bf2f((u16)rv0[kk][j]), 0.f);
                acc[kk * 8 + j] += fmaxf(bf2f((u16)xv1[kk][j]) + bf2f((u16)rv1[kk][j]), 0.f);
            }
    }
    if (p < pend) {
        const int v = srcrid[p];
        const int s = v >> 6, r = v & 63;
        const u16* xp = x + (size_t)s * HID + kg;
        #pragma unroll
        for (int kk = 0; kk < 4; ++kk) {
            short8 xv = *(const short8*)(xp + kk * 32);
            short8 rv = *(const short8*)(&rel[r * 128 + (((kq + kk * 4) ^ (r & 7)) * 8)]);
            #pragma unroll
            for (int j = 0; j < 8; ++j)
                acc[kk * 8 + j] += fmaxf(bf2f((u16)xv[j]) + bf2f((u16)rv[j]), 0.f);
        }
    }

    // own x row + convert -> A-frags (registers, no LDS)
    short8 a[4];
    {
        const u16* xp = x + (size_t)n * HID + kg;
        #pragma unroll
        for (int kk = 0; kk < 4; ++kk) {
            short8 xv = *(const short8*)(xp + kk * 32);
            short8 t;
            #pragma unroll
            for (int j = 0; j < 8; ++j) t[j] = (short)f2bf(acc[kk * 8 + j] + bf2f((u16)xv[j]));
            a[kk] = t;
        }
    }

    // MFMA conv
    f32x4 accm[8];
    #pragma unroll
    for (int nb = 0; nb < 8; ++nb) accm[nb] = (f32x4){0.f, 0.f, 0.f, 0.f};
    #pragma unroll
    for (int nb = 0; nb < 8; ++nb) {
        const u16* wr = w + (size_t)(nb * 16 + r15) * HID + kg;
        #pragma unroll
        for (int kk = 0; kk < 4; ++kk) {
            short8 bv = *(const short8*)(wr + kk * 32);
            accm[nb] = __builtin_amdgcn_mfma_f32_16x16x32_bf16(a[kk], bv, accm[nb], 0, 0, 0);
        }
    }
    const int ob = blockIdx.x * 64 + wid * 16 + (lane >> 4) * 4;
    #pragma unroll
    for (int nb = 0; nb < 8; ++nb) {
        const int col = nb * 16 + r15;
        const float bn = bf2f(bias[col]);
        #pragma unroll
        for (int r = 0; r < 4; ++r) {
            float v = accm[nb][r] + bn;
            if (do_relu) v = fmaxf(v, 0.f);
            out[(size_t)(ob + r) * HID + col] = f2bf(v);
        }
    }
}

// ---------------------------------------------------------------------------
// heads precompute:  y (bf16) [n][0:64]=x2.ew_src, [64:128]=x2.ew_dst;
//                    node_out[n] = x2[n].nw + nb  (f32)
// ---------------------------------------------------------------------------
__global__ __launch_bounds__(256) void k_heads(
    const u16* __restrict__ x2, const u16* __restrict__ ew,
    const u16* __restrict__ nw, const u16* __restrict__ nbias,
    u16* __restrict__ y, float* __restrict__ node_out)
{
    const int wid = threadIdx.x >> 6, lane = threadIdx.x & 63;
    const int r15 = lane & 15, kg = (lane >> 4) * 8;
    const int arow = blockIdx.x * 64 + wid * 16 + r15;
    const u16* xr = x2 + (size_t)arow * HID + kg;
    short8 a[4];
    #pragma unroll
    for (int kk = 0; kk < 4; ++kk) a[kk] = *(const short8*)(xr + kk * 32);

    f32x4 accs[4], accd[4], accn;
    #pragma unroll
    for (int nb = 0; nb < 4; ++nb) {
        accs[nb] = (f32x4){0.f, 0.f, 0.f, 0.f};
        accd[nb] = (f32x4){0.f, 0.f, 0.f, 0.f};
    }
    accn = (f32x4){0.f, 0.f, 0.f, 0.f};

    #pragma unroll
    for (int nb = 0; nb < 4; ++nb) {
        const u16* wr = ew + (size_t)(nb * 16 + r15) * 256 + kg;
        #pragma unroll
        for (int kk = 0; kk < 4; ++kk) {
            short8 bs = *(const short8*)(wr + kk * 32);
            short8 bd = *(const short8*)(wr + 128 + kk * 32);
            accs[nb] = __builtin_amdgcn_mfma_f32_16x16x32_bf16(a[kk], bs, accs[nb], 0, 0, 0);
            accd[nb] = __builtin_amdgcn_mfma_f32_16x16x32_bf16(a[kk], bd, accd[nb], 0, 0, 0);
        }
    }
    {
        const u16* wr = nw + (size_t)r15 * HID + kg;
        #pragma unroll
        for (int kk = 0; kk < 4; ++kk) {
            short8 bv = *(const short8*)(wr + kk * 32);
            accn = __builtin_amdgcn_mfma_f32_16x16x32_bf16(a[kk], bv, accn, 0, 0, 0);
        }
    }

    const int ob = blockIdx.x * 64 + wid * 16 + (lane >> 4) * 4;
    #pragma unroll
    for (int nb = 0; nb < 4; ++nb) {
        const int col = nb * 16 + r15;
        #pragma unroll
        for (int r = 0; r < 4; ++r) {
            y[(size_t)(ob + r) * 128 + col] = f2bf(accs[nb][r]);
            y[(size_t)(ob + r) * 128 + 64 + col] = f2bf(accd[nb][r]);
        }
    }
    const float bn = bf2f(nbias[r15]);
    #pragma unroll
    for (int r = 0; r < 4; ++r)
        node_out[(size_t)(ob + r) * NCLS + r15] = accn[r] + bn;
}

// ---------------------------------------------------------------------------
// edge output: out[e][c] = y[src[e]][c] + y[dst[e]][64+c] + eb[c]  (y bf16)
// ---------------------------------------------------------------------------
__global__ __launch_bounds__(256) void k_eout(
    const u16* __restrict__ y, const int* __restrict__ src, const int* __restrict__ dst,
    const float* __restrict__ eb, float* __restrict__ out)
{
    const int t = blockIdx.x * 256 + threadIdx.x;
    const int e = t >> 2;
    const int qq = (t & 3) * 16;
    const int s = src[e], d = dst[e];
    const u16* ys = y + (size_t)s * 128 + qq;
    const u16* yd = y + (size_t)d * 128 + 64 + qq;
    const float* ebp = eb + qq;
    float* op = out + (size_t)e * 64 + qq;
    #pragma unroll
    for (int c = 0; c < 2; ++c) {
        short8 vs = *(const short8*)(ys + c * 8);
        short8 vd = *(const short8*)(yd + c * 8);
        #pragma unroll
        for (int h = 0; h < 2; ++h) {
            f32x4 vb = *(const f32x4*)(ebp + c * 8 + h * 4);
            f32x4 r;
            #pragma unroll
            for (int j = 0; j < 4; ++j)
                r[j] = bf2f((u16)vs[h * 4 + j]) + bf2f((u16)vd[h * 4 + j]) + vb[j];
            *(f32x4*)(op + c * 8 + h * 4) = r;
        }
    }
}

// ---------------------------------------------------------------------------
__global__ void k_motif(const u16* __restrict__ x2, const int* __restrict__ centers,
                        const u16* __restrict__ mw, const u16* __restrict__ mb,
                        float* __restrict__ out)
{
    __shared__ float xs[HID];
    const int c = blockIdx.x, m = threadIdx.x;
    if (m < HID) xs[m] = bf2f(x2[(size_t)centers[c] * HID + m]);
    __syncthreads();
    const u16* wr = mw + (size_t)m * HID;
    float acc = bf2f(mb[m]);
    #pragma unroll
    for (int k0 = 0; k0 < HID; k0 += 8) {
        short8 wv = *(const short8*)(wr + k0);
        #pragma unroll
        for (int j = 0; j < 8; ++j) acc += xs[k0 + j] * bf2f((u16)wv[j]);
    }
    out[(size_t)c * N_MOTIFS + m] = acc;
}

// ---------------------------------------------------------------------------
extern "C" void kernel_launch(void* const* d_in, const int* in_sizes, int n_in,
                              void* d_out, int out_size, void* d_ws, size_t ws_size,
                              hipStream_t stream)
{
    const float* node_emb = (const float*)d_in[0];
    const float* rel_emb  = (const float*)d_in[1];
    const float* lin_w    = (const float*)d_in[2];
    const float* lin_b    = (const float*)d_in[3];
    const float* conv1_w  = (const float*)d_in[4];
    const float* conv1_b  = (const float*)d_in[5];
    const float* conv2_w  = (const float*)d_in[6];
    const float* conv2_b  = (const float*)d_in[7];
    const float* edge_w   = (const float*)d_in[8];
    const float* edge_b   = (const float*)d_in[9];
    const float* motif_w  = (const float*)d_in[10];
    const float* motif_b  = (const float*)d_in[11];
    const float* node_w   = (const float*)d_in[12];
    const float* node_b   = (const float*)d_in[13];
    const int* node_ids = (const int*)d_in[14];
    const int* rel_ids  = (const int*)d_in[15];
    const int* centers  = (const int*)d_in[16];
    const int* src      = (const int*)d_in[17];             // edge_index[0]
    const int* dst      = ((const int*)d_in[17]) + N_EDGES; // edge_index[1]

    // workspace layout (~160 MB):
    char* ws = (char*)d_ws;
    float* rel_lin = (float*)ws;                                  // 32 KB
    u16*   wb      = (u16*)(ws + 32768);                          // 268 KB
    u16*   rel_bf  = (u16*)(ws + 393216);                         // 16 KB
    u16*   x0      = (u16*)(ws + 524288);                         // 51.2 MB
    u16*   x1      = (u16*)(ws + 524288 + 51200000);              // 51.2 MB
    u16*   y       = (u16*)(ws + 524288 + 2 * 51200000);          // 51.2 MB bf16
    char*  csr     = ws + 524288 + 3 * 51200000;
    int*   deg     = (int*)csr;                                   // 800000
    int*   cur     = (int*)(csr + 800000);                        // 800000
    int*   row_ptr = (int*)(csr + 1600000);                       // 800004
    int*   srcrid  = (int*)(csr + 2400032);                       // 2400000
    int*   bsum    = (int*)(csr + 4800032);                       // 1564
    u16*   x2      = x0;

    float* out_edge  = (float*)d_out;                            // [600000][64]
    float* out_motif = out_edge + (size_t)N_EDGES * 64;          // [256][512]
    float* out_node  = out_motif + (size_t)N_CENTERS * N_MOTIFS; // [200000][16]

    k_pre<<<64 + (N_WB + 127) / 128, 128, 0, stream>>>(
        rel_emb, lin_w, lin_b, conv1_w, conv1_b, conv2_w, conv2_b,
        edge_w, edge_b, motif_w, motif_b, node_w, node_b, rel_lin, rel_bf, wb);
    hipMemsetAsync(deg, 0, 1600000, stream);   // deg + cur

    // CSR build
    k_hist<<<(N_EDGES + 255) / 256, 256, 0, stream>>>(dst, deg);
    k_scan1<<<NB_SCAN, 256, 0, stream>>>(deg, bsum);
    k_scan2<<<1, 512, 0, stream>>>(bsum, row_ptr);
    k_scan3<<<NB_SCAN, 256, 0, stream>>>(deg, bsum, row_ptr);
    k_fill<<<(N_EDGES + 255) / 256, 256, 0, stream>>>(src, dst, rel_ids, row_ptr, cur, srcrid);

    k_lin<<<N_NODES / 64, 256, 0, stream>>>(node_emb, node_ids, wb + O_LINW, wb + O_LINB, x0);

    k_fuse<<<N_NODES / 64, 256, 0, stream>>>(x0, rel_bf, row_ptr, srcrid,
                                             wb + O_C1W, wb + O_C1B, x1, 1);
    k_fuse<<<N_NODES / 64, 256, 0, stream>>>(x1, rel_bf, row_ptr, srcrid,
                                             wb + O_C2W, wb + O_C2B, x2, 0);

    k_heads<<<N_NODES / 64, 256, 0, stream>>>(x2, wb + O_EW, wb + O_NW, wb + O_NB, y, out_node);
    k_eout<<<(N_EDGES * 4) / 256, 256, 0, stream>>>(y, src, dst, edge_b, out_edge);
    k_motif<<<N_CENTERS, N_MOTIFS, 0, stream>>>(x2, centers, wb + O_MW, wb + O_MB, out_motif);
}